// Round 5
// baseline (673.287 us; speedup 1.0000x reference)
//
#include <hip/hip_runtime.h>
#include <stdint.h>

typedef unsigned short u16;
typedef unsigned int   u32;
typedef short bf16x8 __attribute__((ext_vector_type(8)));
typedef float f32x4  __attribute__((ext_vector_type(4)));

#define N_    64
#define CIN_  64
#define T_    256
#define V_    25
#define COUT_ 128
#define CI_   64
#define EPS_  1e-5f
#define CNT_  409600.0f

#define MFMA16(a,b,c) __builtin_amdgcn_mfma_f32_16x16x32_bf16((a),(b),(c),0,0,0)

__device__ __forceinline__ u16 f2bf(float f) {
  u32 u = __float_as_uint(f);
  u += 0x7fffu + ((u >> 16) & 1u);   // RNE
  return (u16)(u >> 16);
}
__device__ __forceinline__ float bf2f(u16 h) { return __uint_as_float(((u32)h) << 16); }

// ---------------- K0: pack weights to bf16 + n-independent rsum ----------------
__global__ __launch_bounds__(256) void k_pack(const float* __restrict__ Wp, const float* __restrict__ Wm4,
                                              const float* __restrict__ dW, const float* __restrict__ A,
                                              const float* __restrict__ Al,
                                              u16* __restrict__ w5, u16* __restrict__ bst,
                                              float* __restrict__ rsumw) {
  int tid = threadIdx.x;
  for (int i = tid; i < 640 * 64; i += 256) {
    int r = i >> 6, k = i & 63;
    float v = (r < 384) ? Wp[i] : (r < 512) ? Wm4[(r - 384) * 64 + k] : dW[(r - 512) * 64 + k];
    w5[i] = f2bf(v);
  }
  for (int i = tid; i < 3 * 32 * 32; i += 256) {
    int s = i >> 10, rem = i & 1023, u = rem >> 5, v = rem & 31;
    float val = (u < 25 && v < 25) ? (A[(s * 25 + u) * 25 + v] + Al[(s * 25 + u) * 25 + v]) : 0.f;
    bst[i] = f2bf(val);
  }
  if (tid < 75) {
    int s = tid / 25, u = tid % 25;
    float acc = 0.f;
    for (int v = 0; v < 25; v++) acc += A[(s * 25 + u) * 25 + v] + Al[(s * 25 + u) * 25 + v];
    rsumw[tid] = acc;
  }
}

// ---------------- K1: temporal means of x (forward / backward windows) ----------------
__global__ __launch_bounds__(256) void k_means(const float* __restrict__ x,
                                               float* __restrict__ mf, float* __restrict__ mb) {
  int i = blockIdx.x, n = blockIdx.y;
  const float* src = x + ((size_t)n * CIN_ + i) * T_ * V_;
  __shared__ float xs[T_ * V_];
  __shared__ float pf[8][32], pb[8][32];
  {
    float4* xs4 = (float4*)xs;
    const float4* src4 = (const float4*)src;
    for (int idx = threadIdx.x; idx < (T_ * V_) / 4; idx += 256) xs4[idx] = src4[idx];
  }
  __syncthreads();
  int v = threadIdx.x & 31, g = threadIdx.x >> 5;
  float sf = 0.f, sb = 0.f;
  if (v < V_) {
    for (int t = g; t < T_; t += 8) {
      float val = xs[t * V_ + v];
      if (t < T_ - 2) sf += val;
      if (t >= 2)     sb += val;
    }
  }
  pf[g][v] = sf; pb[g][v] = sb;
  __syncthreads();
  if (threadIdx.x < V_) {
    float af = 0.f, ab = 0.f;
    for (int gg = 0; gg < 8; gg++) { af += pf[gg][threadIdx.x]; ab += pb[gg][threadIdx.x]; }
    size_t o = ((size_t)n * CIN_ + i) * V_ + threadIdx.x;
    mf[o] = af * (1.0f / 254.0f);
    mb[o] = ab * (1.0f / 254.0f);
  }
}

// ---------------- K2a: per-n GEMVs -> P,Q (64 blocks) ----------------
__global__ __launch_bounds__(256) void k_rd1(
    const float* __restrict__ mf, const float* __restrict__ mb,
    const float* __restrict__ Wm1, const float* __restrict__ bm1,
    const float* __restrict__ Wm2, const float* __restrict__ bm2,
    const float* __restrict__ Wm3, float* __restrict__ pqws) {
  int n = blockIdx.x, tid = threadIdx.x;
  __shared__ float MfL[CIN_][V_], MbL[CIN_][V_], xfL[CI_][V_], xbL[CI_][V_];
  for (int idx = tid; idx < CIN_ * V_; idx += 256) {
    MfL[idx / V_][idx % V_] = mf[(size_t)n * CIN_ * V_ + idx];
    MbL[idx / V_][idx % V_] = mb[(size_t)n * CIN_ * V_ + idx];
  }
  __syncthreads();
  for (int idx = tid; idx < CI_ * V_; idx += 256) {
    int o = idx / V_, v = idx % V_;
    float af = bm1[o], ab = bm2[o];
    for (int i = 0; i < CIN_; i++) {
      af += Wm1[o * CIN_ + i] * MfL[i][v];
      ab += Wm2[o * CIN_ + i] * MbL[i][v];
    }
    xfL[o][v] = af; xbL[o][v] = ab;
  }
  __syncthreads();
  for (int idx = tid; idx < COUT_ * V_; idx += 256) {
    int c = idx / V_, u = idx % V_;
    float p = 0.f, q = 0.f;
    for (int i = 0; i < CI_; i++) {
      p += Wm3[c * CI_ + i] * xbL[i][u];
      q += Wm3[c * CI_ + i] * xfL[i][u];
    }
    pqws[(size_t)n * 6400 + idx] = p;
    pqws[(size_t)n * 6400 + 3200 + idx] = q;
  }
}

// ---------------- K2b: tanh + rdws/biasws (512 blocks: 8 channel-groups x 64 n) ----------------
__global__ __launch_bounds__(256) void k_rd2(
    const float* __restrict__ pqws, const float* __restrict__ rsumw,
    const float* __restrict__ bm3, const float* __restrict__ bm4,
    const float* __restrict__ bp, const float* __restrict__ alpha,
    u16* __restrict__ rdws, float* __restrict__ biasws) {
  int cg = blockIdx.x, n = blockIdx.y;
  int c0 = cg * 16, tid = threadIdx.x;
  __shared__ float Ps[400], Qs[400], rs[75];
  for (int idx = tid; idx < 400; idx += 256) {
    Ps[idx] = pqws[(size_t)n * 6400 + c0 * 25 + idx];
    Qs[idx] = pqws[(size_t)n * 6400 + 3200 + c0 * 25 + idx];
  }
  if (tid < 75) rs[tid] = rsumw[tid];
  __syncthreads();
  float al = alpha[0];
  for (int r = tid; r < 400; r += 256) {
    int cl = r / 25, u = r - cl * 25, c = c0 + cl;
    float pv = Ps[r] + bm3[c];
    float acc = 0.f;
    u16* dst = rdws + ((size_t)(n * COUT_ + c) * 25 + u) * 32;
    for (int w0 = 0; w0 < 25; w0++) {
      float val = al * tanhf(pv - Qs[cl * 25 + w0]);
      dst[w0] = f2bf(val);
      acc += val;
    }
    for (int w0 = 25; w0 < 32; w0++) dst[w0] = 0;
    float yb = 0.f;
    for (int s = 0; s < 3; s++) yb += bp[s * COUT_ + c] * rs[s * 25 + u];
    biasws[(size_t)(n * COUT_ + c) * 25 + u] = bm4[c] * acc + yb;
  }
}

// ---------------- K3: fused MFMA main pass (512 threads / 8 waves) ----------------
// Register wall discovery (rounds 2/4): reported VGPR_Count is arch-VGPRs only; the unified
// VGPR+AGPR budget at (256,2) is 256/wave -> 2 blocks/CU (22% occ). 4-wave decomposition
// needs ~200 live regs -> capping at 128 (round 2) spilled ~1GB/dispatch. So: 8-wave blocks,
// halving per-wave footprint (xf 56->32, acc 32->16, rdf 64->32; ~115 peak) under a 128-reg
// cap via __launch_bounds__(512,4): 2 blocks x 8 waves = 16 waves/CU (~50% occ).
// LDS: staging/XpL union 36,864 + d-buffer 13,056 + stats 2,048 = 51,968 B (2 blocks OK).
// d is merged with y at the epilogue into ONE u32 store/element (was 2x scattered u16):
// WRITE_SIZE 322 -> ~215 MB.
__global__ __launch_bounds__(512, 4) void k_main(
    const float* __restrict__ x, const u16* __restrict__ w5, const u16* __restrict__ bst,
    const u16* __restrict__ rdws, const float* __restrict__ biasws,
    u16* __restrict__ out16, float* __restrict__ partials) {
  __shared__ __align__(16) char smem[36864];
  __shared__ u16 dls[16 * 408];        // d slab, per-g: [ch16][p 400 pad->408]
  __shared__ float statsL[512];
  const int tid = threadIdx.x;
  const int w = tid >> 6, l = tid & 63;
  const int lc = l & 15, lq = l >> 4;
  const int n = blockIdx.y, tc = blockIdx.x, t0 = tc * 16;

  // BsT B-frags (shared by all groups)
  bf16x8 bw[3][2];
  #pragma unroll
  for (int s = 0; s < 3; s++)
    #pragma unroll
    for (int ut = 0; ut < 2; ut++)
      bw[s][ut] = *(const bf16x8*)(bst + (s * 32 + ut * 16 + lc) * 32 + lq * 8);

  // phase 0: stage x in two K-halves (32 channels each), load xf frags per half.
  // row p: 16 u32 (= 32 bf16 channels), col-XOR swizzle f(p) = (p^(p>>2))&3 on u32-quads.
  bf16x8 xf[4][2] = {};
  const float* xb = x + (size_t)n * CIN_ * T_ * V_ + (size_t)t0 * V_;
  #pragma unroll
  for (int ks = 0; ks < 2; ks++) {
    u32* xslw = (u32*)smem;
    for (int idx = tid; idx < 16 * 416; idx += 512) {
      int i2 = idx / 416, p = idx - i2 * 416;
      float a = 0.f, b = 0.f;
      int ch = ks * 32 + 2 * i2;
      if (p < 400) {
        a = xb[(size_t)ch       * (T_ * V_) + p];
        b = xb[(size_t)(ch + 1) * (T_ * V_) + p];
      }
      int f = (p ^ (p >> 2)) & 3;
      xslw[p * 16 + (i2 ^ (f << 2))] = ((u32)f2bf(b) << 16) | (u32)f2bf(a);
    }
    __syncthreads();
    #pragma unroll
    for (int pi = 0; pi < 4; pi++) {
      int pt = w + pi * 8;
      if (pt < 26) {
        int p = pt * 16 + lc;
        int f = (p ^ (p >> 2)) & 3;
        xf[pi][ks] = *(const bf16x8*)((const u16*)smem + p * 32 + ((lq ^ f) << 3));
      }
    }
    __syncthreads();
  }

  // zero XpL region (pads must be 0) + statsL
  {
    uint4 z4 = {0, 0, 0, 0};
    uint4* q = (uint4*)smem;
    for (int idx = tid; idx < 2304; idx += 512) q[idx] = z4;
    statsL[tid] = 0.f;
  }
  __syncthreads();

  u16* xpl = (u16*)smem;   // [c16][t16][72]: slot0 32 + slot1 32 + pad 8
  const f32x4 zz = {0.f, 0.f, 0.f, 0.f};
  u32* out32 = (u32*)out16;

  for (int g = 0; g < 8; g++) {
    const int c0 = g * 16;
    f32x4 acc[2][2];
    #pragma unroll
    for (int cl = 0; cl < 2; cl++) { acc[cl][0] = zz; acc[cl][1] = zz; }

    #pragma unroll
    for (int h = 0; h < 2; h++) {
      const int nsl = h ? 3 : 2;
      // ---- stage A: slabs h*2 .. h*2+nsl-1 (si-outer keeps pressure low) ----
      bf16x8 af[3][2];
      #pragma unroll
      for (int si = 0; si < 3; si++) if (si < nsl) {
        int sl = h * 2 + si;
        #pragma unroll
        for (int ks = 0; ks < 2; ks++)
          af[si][ks] = *(const bf16x8*)(w5 + ((sl * 128 + c0 + lc) * 64 + ks * 32 + lq * 8));
      }
      #pragma unroll
      for (int si = 0; si < 3; si++) if (si < nsl) {
        int sl = h * 2 + si;
        #pragma unroll
        for (int pi = 0; pi < 4; pi++) {
          int pt = w + pi * 8;
          if (pt >= 26) continue;
          f32x4 pa = MFMA16(af[si][0], xf[pi][0], zz);
          pa = MFMA16(af[si][1], xf[pi][1], pa);
          int p = pt * 16 + lc;
          if (p < 400) {
            u32 up = (u32)p, t = up / 25u, v = up - t * 25u;
            if (sl < 4) {
              int slot = sl & 1;
              u16* dst = xpl + (4 * lq) * 1152 + t * 72 + slot * 32 + v;
              #pragma unroll
              for (int r = 0; r < 4; r++) dst[r * 1152] = f2bf(pa[r]);
            } else {  // d slab -> LDS buffer (merged with y at epilogue)
              u16* dd = dls + (4 * lq) * 408 + p;
              #pragma unroll
              for (int r = 0; r < 4; r++) dd[r * 408] = f2bf(pa[r]);
            }
          }
        }
      }
      __syncthreads();

      // ---- stage B: ksteps h*2, h*2+1 (wave owns 2 consecutive channels) ----
      {
        bf16x8 rdf0[2], rdf1[2];
        if (h == 1) {
          #pragma unroll
          for (int cl = 0; cl < 2; cl++) {
            size_t rb = (size_t)(n * COUT_ + c0 + w * 2 + cl) * 25;
            rdf0[cl] = *(const bf16x8*)(rdws + (rb + lc) * 32 + lq * 8);
            int u1c = (lc + 16 < 25) ? lc + 16 : 24;
            rdf1[cl] = *(const bf16x8*)(rdws + (rb + u1c) * 32 + lq * 8);
          }
        }
        #pragma unroll
        for (int cl = 0; cl < 2; cl++) {
          int clocal = w * 2 + cl;
          #pragma unroll
          for (int kl = 0; kl < 2; kl++) {
            bf16x8 aX = *(const bf16x8*)(xpl + clocal * 1152 + lc * 72 + kl * 32 + lq * 8);
            int kk = h * 2 + kl;
            bf16x8 b0, b1;
            if (kk < 3) { b0 = bw[kk][0]; b1 = bw[kk][1]; }
            else        { b0 = rdf0[cl];  b1 = rdf1[cl]; }
            acc[cl][0] = MFMA16(aX, b0, acc[cl][0]);
            acc[cl][1] = MFMA16(aX, b1, acc[cl][1]);
          }
        }
      }
      if (h == 1) {  // epilogue: bias, merge d from LDS, one u32 store/elem, all 4 stats
        #pragma unroll
        for (int cl = 0; cl < 2; cl++) {
          int c = c0 + w * 2 + cl;
          size_t bb = (size_t)(n * COUT_ + c) * 25;
          float bias0 = biasws[bb + lc];
          int u1 = lc + 16; bool v1 = u1 < 25;
          float bias1 = biasws[bb + (v1 ? u1 : 24)];
          size_t ob = ((size_t)(n * COUT_ + c) * T_ + t0) * V_;
          const u16* dd = dls + (w * 2 + cl) * 408;
          float sy = 0.f, sq = 0.f, sd = 0.f, sdd = 0.f;
          #pragma unroll
          for (int r = 0; r < 4; r++) {
            int t = 4 * lq + r;
            float y0 = acc[cl][0][r] + bias0;
            u16 d0 = dd[t * 25 + lc];
            out32[ob + t * 25 + lc] = ((u32)d0 << 16) | (u32)f2bf(y0);
            sy += y0; sq += y0 * y0;
            float f0 = bf2f(d0); sd += f0; sdd += f0 * f0;
            if (v1) {
              float y1 = acc[cl][1][r] + bias1;
              u16 d1 = dd[t * 25 + u1];
              out32[ob + t * 25 + u1] = ((u32)d1 << 16) | (u32)f2bf(y1);
              sy += y1; sq += y1 * y1;
              float f1 = bf2f(d1); sd += f1; sdd += f1 * f1;
            }
          }
          #pragma unroll
          for (int off = 1; off < 64; off <<= 1) {
            sy += __shfl_xor(sy, off); sq += __shfl_xor(sq, off);
            sd += __shfl_xor(sd, off); sdd += __shfl_xor(sdd, off);
          }
          if (l == 0) {
            atomicAdd(&statsL[c * 4 + 0], sy); atomicAdd(&statsL[c * 4 + 1], sq);
            atomicAdd(&statsL[c * 4 + 2], sd); atomicAdd(&statsL[c * 4 + 3], sdd);
          }
        }
      }
      __syncthreads();
    }
  }
  int bflat = blockIdx.y * 16 + blockIdx.x;
  for (int j = tid; j < 512; j += 512) partials[(size_t)j * 1024 + bflat] = statsL[j];
}

// ---------------- K4a: reduce partials [512][1024] -> colsum[512] ----------------
__global__ __launch_bounds__(256) void k_stats1(const float* __restrict__ partials, float* __restrict__ colsum) {
  int w = threadIdx.x >> 6, l = threadIdx.x & 63;
  for (int ci = 0; ci < 8; ci++) {
    int j = blockIdx.x * 32 + w * 8 + ci;
    float s = 0.f;
    for (int it = 0; it < 16; it++) s += partials[(size_t)j * 1024 + it * 64 + l];
    #pragma unroll
    for (int off = 1; off < 64; off <<= 1) s += __shfl_xor(s, off);
    if (l == 0) colsum[j] = s;
  }
}

// ---------------- K4b: BN affine params ----------------
__global__ __launch_bounds__(128) void k_stats2(
    const float* __restrict__ colsum,
    const float* __restrict__ bn_g, const float* __restrict__ bn_b,
    const float* __restrict__ dn_g, const float* __restrict__ dn_b,
    float* __restrict__ params) {
  int c = threadIdx.x;
  float sy = colsum[c * 4], syy = colsum[c * 4 + 1], sd = colsum[c * 4 + 2], sdd = colsum[c * 4 + 3];
  float muY = sy / CNT_, varY = syy / CNT_ - muY * muY;
  float muD = sd / CNT_, varD = sdd / CNT_ - muD * muD;
  float sY = bn_g[c] * rsqrtf(varY + EPS_);
  float sD = dn_g[c] * rsqrtf(varD + EPS_);
  float off = bn_b[c] - muY * sY + dn_b[c] - muD * sD;
  params[c * 4 + 0] = sY; params[c * 4 + 1] = sD; params[c * 4 + 2] = off;
}

// ---------------- K5: in-place finalize: relu(y*sY + d*sD + off), uint4-vectorized ----------------
__global__ __launch_bounds__(256) void k_final(u32* __restrict__ io, const float* __restrict__ params) {
  int slab = blockIdx.x;             // n*COUT_ + c
  int c = slab & (COUT_ - 1);
  float sY = params[c * 4], sD = params[c * 4 + 1], off = params[c * 4 + 2];
  uint4* io4 = (uint4*)io + (size_t)slab * 1600;
  #pragma unroll
  for (int j = 0; j < 7; j++) {
    int idx = j * 256 + (int)threadIdx.x;
    if (idx < 1600) {
      uint4 wv = io4[idx];
      uint4 o;
      o.x = __float_as_uint(fmaxf(fmaf(bf2f((u16)(wv.x & 0xffffu)), sY, fmaf(bf2f((u16)(wv.x >> 16)), sD, off)), 0.f));
      o.y = __float_as_uint(fmaxf(fmaf(bf2f((u16)(wv.y & 0xffffu)), sY, fmaf(bf2f((u16)(wv.y >> 16)), sD, off)), 0.f));
      o.z = __float_as_uint(fmaxf(fmaf(bf2f((u16)(wv.z & 0xffffu)), sY, fmaf(bf2f((u16)(wv.z >> 16)), sD, off)), 0.f));
      o.w = __float_as_uint(fmaxf(fmaf(bf2f((u16)(wv.w & 0xffffu)), sY, fmaf(bf2f((u16)(wv.w >> 16)), sD, off)), 0.f));
      io4[idx] = o;
    }
  }
}

extern "C" void kernel_launch(void* const* d_in, const int* in_sizes, int n_in,
                              void* d_out, int out_size, void* d_ws, size_t ws_size,
                              hipStream_t stream) {
  const float* x    = (const float*)d_in[0];
  const float* A    = (const float*)d_in[1];
  const float* Al   = (const float*)d_in[2];
  const float* Wp   = (const float*)d_in[3];
  const float* bp   = (const float*)d_in[4];
  const float* Wm1  = (const float*)d_in[5];
  const float* bm1  = (const float*)d_in[6];
  const float* Wm2  = (const float*)d_in[7];
  const float* bm2  = (const float*)d_in[8];
  const float* Wm3  = (const float*)d_in[9];
  const float* bm3  = (const float*)d_in[10];
  const float* Wm4  = (const float*)d_in[11];
  const float* bm4  = (const float*)d_in[12];
  const float* alpha= (const float*)d_in[13];
  const float* bn_g = (const float*)d_in[14];
  const float* bn_b = (const float*)d_in[15];
  const float* dW   = (const float*)d_in[16];
  const float* dn_g = (const float*)d_in[17];
  const float* dn_b = (const float*)d_in[18];

  // workspace layout (bytes, 16B-aligned), total ~16.9 MB (unchanged)
  char* ws = (char*)d_ws;
  float* mf       = (float*)(ws + 0);              //   409,600
  float* mb       = (float*)(ws + 409600);         //   409,600
  u16*   rdws     = (u16*)  (ws + 819200);         // 13,107,200  [n][128][25][32] bf16
  float* biasws   = (float*)(ws + 13926400);       //   819,200   [n][128][25]
  u16*   w5       = (u16*)  (ws + 14745600);       //    81,920   [640][64] bf16
  u16*   bstw     = (u16*)  (ws + 14827520);       //     6,144   [3][32][32] bf16
  float* partials = (float*)(ws + 14833664);       // 2,097,152   [512][1024]
  float* colsum   = (float*)(ws + 16930816);       //     2,048
  float* params   = (float*)(ws + 16932864);       //     2,048
  // stream-order disjoint aliases (pq/rsum consumed before partials/colsum produced):
  float* pqws  = partials;   // 1,638,400  [n][2][128][25], used k_rd1 -> k_rd2
  float* rsumw = colsum;     //       300  [3][25],        used k_pack -> k_rd2

  k_pack <<<dim3(1),       dim3(256), 0, stream>>>(Wp, Wm4, dW, A, Al, w5, bstw, rsumw);
  k_means<<<dim3(64, 64),  dim3(256), 0, stream>>>(x, mf, mb);
  k_rd1  <<<dim3(64),      dim3(256), 0, stream>>>(mf, mb, Wm1, bm1, Wm2, bm2, Wm3, pqws);
  k_rd2  <<<dim3(8, 64),   dim3(256), 0, stream>>>(pqws, rsumw, bm3, bm4, bp, alpha, rdws, biasws);
  k_main <<<dim3(16, 64),  dim3(512), 0, stream>>>(x, w5, bstw, rdws, biasws,
                                                   (u16*)d_out, partials);
  k_stats1<<<dim3(16),     dim3(256), 0, stream>>>(partials, colsum);
  k_stats2<<<dim3(1),      dim3(128), 0, stream>>>(colsum, bn_g, bn_b, dn_g, dn_b, params);
  k_final<<<dim3(64 * 128),dim3(256), 0, stream>>>((u32*)d_out, params);
}

// Round 7
// 632.104 us; speedup vs baseline: 1.0652x; 1.0652x over previous
//
#include <hip/hip_runtime.h>
#include <stdint.h>

typedef unsigned short u16;
typedef unsigned int   u32;
typedef short bf16x8 __attribute__((ext_vector_type(8)));
typedef float f32x4  __attribute__((ext_vector_type(4)));

#define N_    64
#define CIN_  64
#define T_    256
#define V_    25
#define COUT_ 128
#define CI_   64
#define EPS_  1e-5f
#define CNT_  409600.0f

#define MFMA16(a,b,c) __builtin_amdgcn_mfma_f32_16x16x32_bf16((a),(b),(c),0,0,0)

__device__ __forceinline__ u16 f2bf(float f) {
  u32 u = __float_as_uint(f);
  u += 0x7fffu + ((u >> 16) & 1u);   // RNE
  return (u16)(u >> 16);
}
__device__ __forceinline__ float bf2f(u16 h) { return __uint_as_float(((u32)h) << 16); }

// ---------------- K0: pack weights to bf16 + n-independent rsum (8 blocks) ----------------
__global__ __launch_bounds__(256) void k_pack(const float* __restrict__ Wp, const float* __restrict__ Wm4,
                                              const float* __restrict__ dW, const float* __restrict__ A,
                                              const float* __restrict__ Al,
                                              u16* __restrict__ w5, u16* __restrict__ bst,
                                              float* __restrict__ rsumw) {
  int tid = blockIdx.x * 256 + threadIdx.x;
  int stride = gridDim.x * 256;
  for (int i = tid; i < 640 * 64; i += stride) {
    int r = i >> 6, k = i & 63;
    float v = (r < 384) ? Wp[i] : (r < 512) ? Wm4[(r - 384) * 64 + k] : dW[(r - 512) * 64 + k];
    w5[i] = f2bf(v);
  }
  for (int i = tid; i < 3 * 32 * 32; i += stride) {
    int s = i >> 10, rem = i & 1023, u = rem >> 5, v = rem & 31;
    float val = (u < 25 && v < 25) ? (A[(s * 25 + u) * 25 + v] + Al[(s * 25 + u) * 25 + v]) : 0.f;
    bst[i] = f2bf(val);
  }
  if (blockIdx.x == 0 && threadIdx.x < 75) {
    int s = threadIdx.x / 25, u = threadIdx.x % 25;
    float acc = 0.f;
    for (int v = 0; v < 25; v++) acc += A[(s * 25 + u) * 25 + v] + Al[(s * 25 + u) * 25 + v];
    rsumw[threadIdx.x] = acc;
  }
}

// ---------------- K1: temporal means of x (forward / backward windows) ----------------
__global__ __launch_bounds__(256) void k_means(const float* __restrict__ x,
                                               float* __restrict__ mf, float* __restrict__ mb) {
  int i = blockIdx.x, n = blockIdx.y;
  const float* src = x + ((size_t)n * CIN_ + i) * T_ * V_;
  __shared__ float xs[T_ * V_];
  __shared__ float pf[8][32], pb[8][32];
  {
    float4* xs4 = (float4*)xs;
    const float4* src4 = (const float4*)src;
    for (int idx = threadIdx.x; idx < (T_ * V_) / 4; idx += 256) xs4[idx] = src4[idx];
  }
  __syncthreads();
  int v = threadIdx.x & 31, g = threadIdx.x >> 5;
  float sf = 0.f, sb = 0.f;
  if (v < V_) {
    for (int t = g; t < T_; t += 8) {
      float val = xs[t * V_ + v];
      if (t < T_ - 2) sf += val;
      if (t >= 2)     sb += val;
    }
  }
  pf[g][v] = sf; pb[g][v] = sb;
  __syncthreads();
  if (threadIdx.x < V_) {
    float af = 0.f, ab = 0.f;
    for (int gg = 0; gg < 8; gg++) { af += pf[gg][threadIdx.x]; ab += pb[gg][threadIdx.x]; }
    size_t o = ((size_t)n * CIN_ + i) * V_ + threadIdx.x;
    mf[o] = af * (1.0f / 254.0f);
    mb[o] = ab * (1.0f / 254.0f);
  }
}

// ---------------- K2a: per-n GEMVs -> P,Q (64 blocks) ----------------
__global__ __launch_bounds__(256) void k_rd1(
    const float* __restrict__ mf, const float* __restrict__ mb,
    const float* __restrict__ Wm1, const float* __restrict__ bm1,
    const float* __restrict__ Wm2, const float* __restrict__ bm2,
    const float* __restrict__ Wm3, float* __restrict__ pqws) {
  int n = blockIdx.x, tid = threadIdx.x;
  __shared__ float MfL[CIN_][V_], MbL[CIN_][V_], xfL[CI_][V_], xbL[CI_][V_];
  for (int idx = tid; idx < CIN_ * V_; idx += 256) {
    MfL[idx / V_][idx % V_] = mf[(size_t)n * CIN_ * V_ + idx];
    MbL[idx / V_][idx % V_] = mb[(size_t)n * CIN_ * V_ + idx];
  }
  __syncthreads();
  for (int idx = tid; idx < CI_ * V_; idx += 256) {
    int o = idx / V_, v = idx % V_;
    float af = bm1[o], ab = bm2[o];
    for (int i = 0; i < CIN_; i++) {
      af += Wm1[o * CIN_ + i] * MfL[i][v];
      ab += Wm2[o * CIN_ + i] * MbL[i][v];
    }
    xfL[o][v] = af; xbL[o][v] = ab;
  }
  __syncthreads();
  for (int idx = tid; idx < COUT_ * V_; idx += 256) {
    int c = idx / V_, u = idx % V_;
    float p = 0.f, q = 0.f;
    for (int i = 0; i < CI_; i++) {
      p += Wm3[c * CI_ + i] * xbL[i][u];
      q += Wm3[c * CI_ + i] * xfL[i][u];
    }
    pqws[(size_t)n * 6400 + idx] = p;
    pqws[(size_t)n * 6400 + 3200 + idx] = q;
  }
}

// ---------------- K2b: tanh + rdws/biasws (512 blocks: 8 channel-groups x 64 n) ----------------
__global__ __launch_bounds__(256) void k_rd2(
    const float* __restrict__ pqws, const float* __restrict__ rsumw,
    const float* __restrict__ bm3, const float* __restrict__ bm4,
    const float* __restrict__ bp, const float* __restrict__ alpha,
    u16* __restrict__ rdws, float* __restrict__ biasws) {
  int cg = blockIdx.x, n = blockIdx.y;
  int c0 = cg * 16, tid = threadIdx.x;
  __shared__ float Ps[400], Qs[400], rs[75];
  for (int idx = tid; idx < 400; idx += 256) {
    Ps[idx] = pqws[(size_t)n * 6400 + c0 * 25 + idx];
    Qs[idx] = pqws[(size_t)n * 6400 + 3200 + c0 * 25 + idx];
  }
  if (tid < 75) rs[tid] = rsumw[tid];
  __syncthreads();
  float al = alpha[0];
  for (int r = tid; r < 400; r += 256) {
    int cl = r / 25, u = r - cl * 25, c = c0 + cl;
    float pv = Ps[r] + bm3[c];
    float acc = 0.f;
    u16* dst = rdws + ((size_t)(n * COUT_ + c) * 25 + u) * 32;
    for (int w0 = 0; w0 < 25; w0++) {
      float val = al * tanhf(pv - Qs[cl * 25 + w0]);
      dst[w0] = f2bf(val);
      acc += val;
    }
    for (int w0 = 25; w0 < 32; w0++) dst[w0] = 0;
    float yb = 0.f;
    for (int s = 0; s < 3; s++) yb += bp[s * COUT_ + c] * rs[s * 25 + u];
    biasws[(size_t)(n * COUT_ + c) * 25 + u] = bm4[c] * acc + yb;
  }
}

// ---------------- K3: fused MFMA main pass (512 threads / 8 waves, ONE barrier-pair per g) ----------------
// Evidence r0/r4/r5: dur flat ~225us across occ 22%/44% with all pipes <26% busy -> limiter is the
// 36-barrier lockstep micro-phase structure. This version: per channel-group g, stage A computes ALL
// 5 slabs into a full-K xpl [c16][t16][128] (16B-chunk XOR swizzle chunk^=(t&15): stage-B ds_read_b128
// lands 2-way max; exact 64KB, no pad), then ONE barrier, stage B does all 4 K-steps + epilogue, barrier.
// 20 barriers/block (was 36), ~2x work per phase. rdf/bias loads issue pre-barrier (latency absorbed).
// LDS: 65,536 (xpl/staging union) + 12,800 (dls) + 2,048 (stats) = 80,384 -> 2 blocks/CU, 16 waves.
__global__ __launch_bounds__(512, 4) void k_main(
    const float* __restrict__ x, const u16* __restrict__ w5, const u16* __restrict__ bst,
    const u16* __restrict__ rdws, const float* __restrict__ biasws,
    u16* __restrict__ out16, float* __restrict__ partials) {
  __shared__ __align__(16) char smem[65536];
  __shared__ u16 dls[16 * 400];        // d slab, per-g: [ch16][p400]
  __shared__ float statsL[512];
  const int tid = threadIdx.x;
  const int w = tid >> 6, l = tid & 63;
  const int lc = l & 15, lq = l >> 4;
  const int n = blockIdx.y, tc = blockIdx.x, t0 = tc * 16;

  // BsT B-frags (shared by all groups)
  bf16x8 bw[3][2];
  #pragma unroll
  for (int s = 0; s < 3; s++)
    #pragma unroll
    for (int ut = 0; ut < 2; ut++)
      bw[s][ut] = *(const bf16x8*)(bst + (s * 32 + ut * 16 + lc) * 32 + lq * 8);

  // phase 0: stage x in two K-halves (32 channels each), load xf frags per half.
  bf16x8 xf[4][2] = {};
  const float* xb = x + (size_t)n * CIN_ * T_ * V_ + (size_t)t0 * V_;
  #pragma unroll
  for (int ks = 0; ks < 2; ks++) {
    u32* xslw = (u32*)smem;
    for (int idx = tid; idx < 16 * 416; idx += 512) {
      int i2 = idx / 416, p = idx - i2 * 416;
      float a = 0.f, b = 0.f;
      int ch = ks * 32 + 2 * i2;
      if (p < 400) {
        a = xb[(size_t)ch       * (T_ * V_) + p];
        b = xb[(size_t)(ch + 1) * (T_ * V_) + p];
      }
      int f = (p ^ (p >> 2)) & 3;
      xslw[p * 16 + (i2 ^ (f << 2))] = ((u32)f2bf(b) << 16) | (u32)f2bf(a);
    }
    __syncthreads();
    #pragma unroll
    for (int pi = 0; pi < 4; pi++) {
      int pt = w + pi * 8;
      if (pt < 26) {
        int p = pt * 16 + lc;
        int f = (p ^ (p >> 2)) & 3;
        xf[pi][ks] = *(const bf16x8*)((const u16*)smem + p * 32 + ((lq ^ f) << 3));
      }
    }
    __syncthreads();
  }

  // per-pi precompute (g-invariant): p = pt*16+lc -> (t,v); write offsets for swizzled xpl
  bool pvalid[4]; int wbase[4], txm[4], vhi[4], dlsp[4];
  #pragma unroll
  for (int pi = 0; pi < 4; pi++) {
    int pt = w + pi * 8;
    pvalid[pi] = (pt < 25);           // pt==25..31 -> all lanes p>=400
    int p = pt * 16 + lc;
    u32 up = (u32)p, t = up / 25u, v = up - t * 25u;
    wbase[pi] = (int)(t * 128u + (v & 7u));
    txm[pi]   = (int)(t & 15u);
    vhi[pi]   = (int)(v >> 3);
    dlsp[pi]  = p;
  }
  const int u1 = lc + 16;
  const bool v1 = (u1 < 25);
  const int u1c = v1 ? u1 : 24;

  // zero xpl (v-pads 25..31 of each slab must stay 0) + statsL
  {
    uint4 z4 = {0, 0, 0, 0};
    uint4* q = (uint4*)smem;
    for (int idx = tid; idx < 4096; idx += 512) q[idx] = z4;
    statsL[tid] = 0.f;
  }
  __syncthreads();

  u16* xpl = (u16*)smem;   // [c16][t16][128] u16, chunk-swizzled: chunk' = chunk ^ (t&15)
  const f32x4 zz = {0.f, 0.f, 0.f, 0.f};
  u32* out32 = (u32*)out16;

  for (int g = 0; g < 8; g++) {
    const int c0 = g * 16;
    f32x4 acc[2][2];
    #pragma unroll
    for (int cl = 0; cl < 2; cl++) { acc[cl][0] = zz; acc[cl][1] = zz; }

    // ---- stage A: all 5 slabs (0-2: Wp s, 3: Wm4 -> xpl; 4: dW -> dls) ----
    #pragma unroll
    for (int si = 0; si < 5; si++) {
      const u16* wrow = w5 + (size_t)(si * 128 + c0 + lc) * 64;
      bf16x8 af0 = *(const bf16x8*)(wrow + lq * 8);
      bf16x8 af1 = *(const bf16x8*)(wrow + 32 + lq * 8);
      #pragma unroll
      for (int pi = 0; pi < 4; pi++) {
        if (!pvalid[pi]) continue;
        f32x4 pa = MFMA16(af0, xf[pi][0], zz);
        pa = MFMA16(af1, xf[pi][1], pa);
        if (si < 4) {
          int chunk = ((si * 4 + vhi[pi]) ^ txm[pi]) << 3;
          u16* dst = xpl + (4 * lq) * 2048 + wbase[pi] + chunk;
          #pragma unroll
          for (int r = 0; r < 4; r++) dst[r * 2048] = f2bf(pa[r]);
        } else {
          u16* dd = dls + (4 * lq) * 400 + dlsp[pi];
          #pragma unroll
          for (int r = 0; r < 4; r++) dd[r * 400] = f2bf(pa[r]);
        }
      }
    }

    // issue stage-B global loads BEFORE the barrier (latency absorbed by drain)
    bf16x8 rdf0[2], rdf1[2];
    float bias0[2], bias1[2];
    #pragma unroll
    for (int cl = 0; cl < 2; cl++) {
      size_t rb = (size_t)(n * COUT_ + c0 + w * 2 + cl) * 25;
      rdf0[cl] = *(const bf16x8*)(rdws + (rb + lc) * 32 + lq * 8);
      rdf1[cl] = *(const bf16x8*)(rdws + (rb + u1c) * 32 + lq * 8);
      size_t bb = (size_t)(n * COUT_ + c0 + w * 2 + cl) * 25;
      bias0[cl] = biasws[bb + lc];
      bias1[cl] = biasws[bb + u1c];
    }
    __syncthreads();

    // ---- stage B: 4 K-steps per channel + epilogue ----
    #pragma unroll
    for (int cl = 0; cl < 2; cl++) {
      int clocal = w * 2 + cl;
      #pragma unroll
      for (int kk = 0; kk < 4; kk++) {
        bf16x8 aX = *(const bf16x8*)(xpl + clocal * 2048 + lc * 128 + (((kk * 4 + lq) ^ lc) << 3));
        bf16x8 b0, b1;
        if (kk < 3) { b0 = bw[kk][0]; b1 = bw[kk][1]; }
        else        { b0 = rdf0[cl];  b1 = rdf1[cl]; }
        acc[cl][0] = MFMA16(aX, b0, acc[cl][0]);
        acc[cl][1] = MFMA16(aX, b1, acc[cl][1]);
      }
      // epilogue: bias, merge d from LDS, one u32 store/elem, all 4 stats
      int c = c0 + clocal;
      size_t ob = ((size_t)(n * COUT_ + c) * T_ + t0) * V_;
      const u16* dd = dls + clocal * 400;
      float sy = 0.f, sq = 0.f, sd = 0.f, sdd = 0.f;
      #pragma unroll
      for (int r = 0; r < 4; r++) {
        int t = 4 * lq + r;
        float y0 = acc[cl][0][r] + bias0[cl];
        u16 d0 = dd[t * 25 + lc];
        out32[ob + t * 25 + lc] = ((u32)d0 << 16) | (u32)f2bf(y0);
        sy += y0; sq += y0 * y0;
        float f0 = bf2f(d0); sd += f0; sdd += f0 * f0;
        if (v1) {
          float y1 = acc[cl][1][r] + bias1[cl];
          u16 d1 = dd[t * 25 + u1];
          out32[ob + t * 25 + u1] = ((u32)d1 << 16) | (u32)f2bf(y1);
          sy += y1; sq += y1 * y1;
          float f1 = bf2f(d1); sd += f1; sdd += f1 * f1;
        }
      }
      #pragma unroll
      for (int off = 1; off < 64; off <<= 1) {
        sy += __shfl_xor(sy, off); sq += __shfl_xor(sq, off);
        sd += __shfl_xor(sd, off); sdd += __shfl_xor(sdd, off);
      }
      if (l == 0) {
        atomicAdd(&statsL[c * 4 + 0], sy); atomicAdd(&statsL[c * 4 + 1], sq);
        atomicAdd(&statsL[c * 4 + 2], sd); atomicAdd(&statsL[c * 4 + 3], sdd);
      }
    }
    __syncthreads();
  }
  int bflat = blockIdx.y * 16 + blockIdx.x;
  partials[(size_t)tid * 1024 + bflat] = statsL[tid];
}

// ---------------- K4a: reduce partials [512][1024] -> colsum[512] ----------------
__global__ __launch_bounds__(256) void k_stats1(const float* __restrict__ partials, float* __restrict__ colsum) {
  int w = threadIdx.x >> 6, l = threadIdx.x & 63;
  for (int ci = 0; ci < 8; ci++) {
    int j = blockIdx.x * 32 + w * 8 + ci;
    float s = 0.f;
    for (int it = 0; it < 16; it++) s += partials[(size_t)j * 1024 + it * 64 + l];
    #pragma unroll
    for (int off = 1; off < 64; off <<= 1) s += __shfl_xor(s, off);
    if (l == 0) colsum[j] = s;
  }
}

// ---------------- K4b: BN affine params ----------------
__global__ __launch_bounds__(128) void k_stats2(
    const float* __restrict__ colsum,
    const float* __restrict__ bn_g, const float* __restrict__ bn_b,
    const float* __restrict__ dn_g, const float* __restrict__ dn_b,
    float* __restrict__ params) {
  int c = threadIdx.x;
  float sy = colsum[c * 4], syy = colsum[c * 4 + 1], sd = colsum[c * 4 + 2], sdd = colsum[c * 4 + 3];
  float muY = sy / CNT_, varY = syy / CNT_ - muY * muY;
  float muD = sd / CNT_, varD = sdd / CNT_ - muD * muD;
  float sY = bn_g[c] * rsqrtf(varY + EPS_);
  float sD = dn_g[c] * rsqrtf(varD + EPS_);
  float off = bn_b[c] - muY * sY + dn_b[c] - muD * sD;
  params[c * 4 + 0] = sY; params[c * 4 + 1] = sD; params[c * 4 + 2] = off;
}

// ---------------- K5: in-place finalize: relu(y*sY + d*sD + off), uint4-vectorized ----------------
__global__ __launch_bounds__(256) void k_final(u32* __restrict__ io, const float* __restrict__ params) {
  int slab = blockIdx.x;             // n*COUT_ + c
  int c = slab & (COUT_ - 1);
  float sY = params[c * 4], sD = params[c * 4 + 1], off = params[c * 4 + 2];
  uint4* io4 = (uint4*)io + (size_t)slab * 1600;
  #pragma unroll
  for (int j = 0; j < 7; j++) {
    int idx = j * 256 + (int)threadIdx.x;
    if (idx < 1600) {
      uint4 wv = io4[idx];
      uint4 o;
      o.x = __float_as_uint(fmaxf(fmaf(bf2f((u16)(wv.x & 0xffffu)), sY, fmaf(bf2f((u16)(wv.x >> 16)), sD, off)), 0.f));
      o.y = __float_as_uint(fmaxf(fmaf(bf2f((u16)(wv.y & 0xffffu)), sY, fmaf(bf2f((u16)(wv.y >> 16)), sD, off)), 0.f));
      o.z = __float_as_uint(fmaxf(fmaf(bf2f((u16)(wv.z & 0xffffu)), sY, fmaf(bf2f((u16)(wv.z >> 16)), sD, off)), 0.f));
      o.w = __float_as_uint(fmaxf(fmaf(bf2f((u16)(wv.w & 0xffffu)), sY, fmaf(bf2f((u16)(wv.w >> 16)), sD, off)), 0.f));
      io4[idx] = o;
    }
  }
}

extern "C" void kernel_launch(void* const* d_in, const int* in_sizes, int n_in,
                              void* d_out, int out_size, void* d_ws, size_t ws_size,
                              hipStream_t stream) {
  const float* x    = (const float*)d_in[0];
  const float* A    = (const float*)d_in[1];
  const float* Al   = (const float*)d_in[2];
  const float* Wp   = (const float*)d_in[3];
  const float* bp   = (const float*)d_in[4];
  const float* Wm1  = (const float*)d_in[5];
  const float* bm1  = (const float*)d_in[6];
  const float* Wm2  = (const float*)d_in[7];
  const float* bm2  = (const float*)d_in[8];
  const float* Wm3  = (const float*)d_in[9];
  const float* bm3  = (const float*)d_in[10];
  const float* Wm4  = (const float*)d_in[11];
  const float* bm4  = (const float*)d_in[12];
  const float* alpha= (const float*)d_in[13];
  const float* bn_g = (const float*)d_in[14];
  const float* bn_b = (const float*)d_in[15];
  const float* dW   = (const float*)d_in[16];
  const float* dn_g = (const float*)d_in[17];
  const float* dn_b = (const float*)d_in[18];

  // workspace layout (bytes, 16B-aligned), total ~16.9 MB (unchanged)
  char* ws = (char*)d_ws;
  float* mf       = (float*)(ws + 0);              //   409,600
  float* mb       = (float*)(ws + 409600);         //   409,600
  u16*   rdws     = (u16*)  (ws + 819200);         // 13,107,200  [n][128][25][32] bf16
  float* biasws   = (float*)(ws + 13926400);       //   819,200   [n][128][25]
  u16*   w5       = (u16*)  (ws + 14745600);       //    81,920   [640][64] bf16
  u16*   bstw     = (u16*)  (ws + 14827520);       //     6,144   [3][32][32] bf16
  float* partials = (float*)(ws + 14833664);       // 2,097,152   [512][1024]
  float* colsum   = (float*)(ws + 16930816);       //     2,048
  float* params   = (float*)(ws + 16932864);       //     2,048
  // stream-order disjoint aliases (pq/rsum consumed before partials/colsum produced):
  float* pqws  = partials;   // 1,638,400  [n][2][128][25], used k_rd1 -> k_rd2
  float* rsumw = colsum;     //       300  [3][25],        used k_pack -> k_rd2

  k_pack <<<dim3(8),       dim3(256), 0, stream>>>(Wp, Wm4, dW, A, Al, w5, bstw, rsumw);
  k_means<<<dim3(64, 64),  dim3(256), 0, stream>>>(x, mf, mb);
  k_rd1  <<<dim3(64),      dim3(256), 0, stream>>>(mf, mb, Wm1, bm1, Wm2, bm2, Wm3, pqws);
  k_rd2  <<<dim3(8, 64),   dim3(256), 0, stream>>>(pqws, rsumw, bm3, bm4, bp, alpha, rdws, biasws);
  k_main <<<dim3(16, 64),  dim3(512), 0, stream>>>(x, w5, bstw, rdws, biasws,
                                                   (u16*)d_out, partials);
  k_stats1<<<dim3(16),     dim3(256), 0, stream>>>(partials, colsum);
  k_stats2<<<dim3(1),      dim3(128), 0, stream>>>(colsum, bn_g, bn_b, dn_g, dn_b, params);
  k_final<<<dim3(64 * 128),dim3(256), 0, stream>>>((u32*)d_out, params);
}